// Round 7
// baseline (575.611 us; speedup 1.0000x reference)
//
#include <hip/hip_runtime.h>
#include <hip/hip_bf16.h>

// GCN_5016521802361: 2x SAGEConv(aggr='lstm', project=True), N=50000, D=16, F=128, C=40.
// Round 20:
//  - fused_lin_xp_y ELIMINATED: lstm1 becomes EPI=2 with an epilogue computing,
//    for its own 16 nodes: h1 = relu(h@Wl1^T+bl1+x@Wr1^T) (all 8 waves, col
//    j=w*16+lid), xp2 = relu(h1@Wp2^T+bp2), Y2 = xp2@Wihp2^T+bsum2 (4 col-tiles
//    per wave). X rows (contiguous 4KB) DMA'd into dead stage[0] during t=15.
//    Kills 1 kernel + aggr roundtrip + X re-read. Y2 goes to a separate buffer
//    (in-place would race with other blocks' Y1 gathers).
//  - Epilogue row-stage DMAs (X here, h1 in EPI=1) use rule-21 pre-swizzle:
//    global src chunk = lid ^ (row&7), linear LDS dest, XOR on read ->
//    removes the 16-way lid*256B bank conflict (r19's +1.3M counter).
//  - lstm core + producers otherwise r19-exact.

typedef __hip_bfloat16 bf16;
typedef __attribute__((ext_vector_type(8))) short short8;
typedef __attribute__((ext_vector_type(4))) short short4v;
typedef __attribute__((ext_vector_type(4))) float floatx4;
typedef __attribute__((ext_vector_type(4))) float float4v;

#define LOG2E 1.4426950408889634f
#define TWOL  2.8853900817779268f

__device__ __forceinline__ float bf2f(bf16 v) { return __bfloat162float(v); }
__device__ __forceinline__ bf16  f2bf(float v) { return __float2bfloat16(v); }
__device__ __forceinline__ float bfs2f(short s) {
    union { float f; unsigned u; } v; v.u = ((unsigned)(unsigned short)s) << 16; return v.f;
}
__device__ __forceinline__ short f2bfs(float v) {
    bf16 b = __float2bfloat16(v); return *(short*)&b;
}

__device__ __forceinline__ float ex2(float x) {
#if __has_builtin(__builtin_amdgcn_exp2f)
    return __builtin_amdgcn_exp2f(x);
#else
    return exp2f(x);
#endif
}

// LSTM cell, prescaled inputs: i_,f_,o_ carry log2e, g_ carries 2*log2e,
// c is tracked as (2*log2e)*c_true. Single merged rcp on the c path.
__device__ __forceinline__ float cell(float i_, float f_, float g_, float o_, float& c) {
    float ei = ex2(-i_), ef = ex2(-f_), eg = ex2(g_), eo = ex2(-o_);
    float A = (1.f + ei) * (eg + 1.f);
    float B = 1.f + ef;
    float cn = fmaf(c, A, fmaf(eg, TWOL, -TWOL) * B) * __builtin_amdgcn_rcpf(A * B);
    c = cn;
    float ec = ex2(cn);
    return (ec - 1.f) * __builtin_amdgcn_rcpf((ec + 1.f) * (1.f + eo));
}

// Permuted-Y memory position p -> source gate row. Convert-time only.
__device__ __forceinline__ int ydecode(int p) {
    int pw = (p >> 6) & 7, pq = (p >> 4) & 3, pg = (p >> 2) & 3, pr = p & 3;
    return pg * 128 + pw * 16 + pq * 4 + pr;
}

__device__ __forceinline__ void dma1(const bf16* gp, void* lp) {
    __builtin_amdgcn_global_load_lds(
        (const __attribute__((address_space(1))) void*)gp,
        (__attribute__((address_space(3))) void*)lp, 16, 0, 0);
}

__device__ __forceinline__ void dma2(const bf16* gp, void* lp0, void* lp1) {
    dma1(gp, lp0);
    dma1(gp + 32, lp1);
}

// mode 0: plain copy; mode 1: Whh gate-scale; mode 2: Wih permute+scale;
// mode 3: bias pair sum -> f32 dst (permuted+scaled)
struct Cvt { const void* src; const void* src2; bf16* dst; int n; int mode; };
struct CvtAll { Cvt t[17]; };

__global__ void convert_inputs(CvtAll ca, int* __restrict__ flag) {
    __shared__ int sflag;
    {
        const unsigned short* xb = (const unsigned short*)ca.t[0].src;
        int cnt = 0;
        for (int i = threadIdx.x; i < 1024; i += blockDim.x) {
            int e = (xb[i] >> 7) & 0xFF;
            cnt += (e >= 0xC8);
        }
        if (threadIdx.x == 0) sflag = 0;
        __syncthreads();
        if (cnt) atomicAdd(&sflag, cnt);
        __syncthreads();
    }
    const bool isf32 = (sflag >= 16);
    if (blockIdx.x == 0 && threadIdx.x == 0) *flag = isf32 ? 1 : 0;

    const int stride = gridDim.x * blockDim.x;
    const int tid0 = blockIdx.x * blockDim.x + threadIdx.x;
#pragma unroll 1
    for (int k = 0; k < 17; k++) {
        const int n = ca.t[k].n, mode = ca.t[k].mode;
        if (mode == 3) {
            const float* a32 = (const float*)ca.t[k].src;
            const float* b32 = (const float*)ca.t[k].src2;
            const short* a16 = (const short*)ca.t[k].src;
            const short* b16 = (const short*)ca.t[k].src2;
            float* df = (float*)ca.t[k].dst;
            for (int i = tid0; i < n; i += stride) {
                int yd = ydecode(i);
                float va = isf32 ? a32[yd] : bfs2f(a16[yd]);
                float vb = isf32 ? b32[yd] : bfs2f(b16[yd]);
                float m = ((((unsigned)i >> 2) & 3) == 2) ? TWOL : LOG2E;
                df[i] = (va + vb) * m;
            }
            continue;
        }
        const int n8 = n >> 3;
        bf16* d = ca.t[k].dst;
        for (int i = tid0; i < n8; i += stride) {
            int si = i;
            float m = 1.f;
            bool scaled = false;
            if (mode == 1) {
                m = ((((unsigned)i >> 11) & 3) == 2) ? TWOL : LOG2E; scaled = true;
            } else if (mode == 2) {
                int row = i >> 4;
                si = ydecode(row) * 16 + (i & 15);
                m = ((((unsigned)row >> 2) & 3) == 2) ? TWOL : LOG2E; scaled = true;
            }
            short8 ov;
            if (isf32) {
                const float4v* sp = (const float4v*)ca.t[k].src;
                float4v a = sp[2 * si], b = sp[2 * si + 1];
#pragma unroll
                for (int j = 0; j < 4; j++) {
                    ov[j]     = f2bfs(a[j] * m);
                    ov[4 + j] = f2bfs(b[j] * m);
                }
            } else {
                short8 sv = ((const short8*)ca.t[k].src)[si];
                if (scaled) {
#pragma unroll
                    for (int j = 0; j < 8; j++) ov[j] = f2bfs(bfs2f(sv[j]) * m);
                } else ov = sv;
            }
            ((short8*)d)[i] = ov;
        }
        if (mode == 0)
            for (int i = (n8 << 3) + tid0; i < n; i += stride) {
                float v = isf32 ? ((const float*)ca.t[k].src)[i]
                                : bfs2f(((const short*)ca.t[k].src)[i]);
                d[i] = f2bf(v);
            }
    }
}

// ---------------------------------------------------------------------------
// Fused layer entry: Y = (relu(X@Wp^T+bp)) @ Wihp^T(+bsum), permuted layout.
// Stage B: wave w owns col chunk w; weights loaded once, reused over 4 rowtiles.
// ---------------------------------------------------------------------------
__global__ __launch_bounds__(256, 2) void fused_xp_y(
    const bf16* __restrict__ X, const bf16* __restrict__ Wp, const bf16* __restrict__ bp,
    const bf16* __restrict__ Wihp, const float* __restrict__ bsum,
    bf16* __restrict__ Yout, int N)
{
    __shared__ bf16 T[64][136];
    const int tid = threadIdx.x;
    const int w = tid >> 6, l = tid & 63, q = l >> 4, lid = l & 15;
    const int rowbase = blockIdx.x * 64;

    int arow = rowbase + w * 16 + lid;
    if (arow >= N) arow = N - 1;

    floatx4 acc[8];
    short8 bfrag[8][4];
    float bvv[8];

    // ---- stage A: xp = relu(X@Wp^T + bp) -> T (cols lid*8+ct) ----
#pragma unroll
    for (int ct = 0; ct < 8; ct++) acc[ct] = (floatx4)(0.f);
#pragma unroll
    for (int ct = 0; ct < 8; ct++) {
        int j = lid * 8 + ct;
        bvv[ct] = bf2f(bp[j]);
#pragma unroll
        for (int kt = 0; kt < 4; kt++)
            bfrag[ct][kt] = *(const short8*)(Wp + (size_t)j * 128 + kt * 32 + q * 8);
    }
#pragma unroll
    for (int kt = 0; kt < 4; kt++) {
        short8 af = *(const short8*)(X + (size_t)arow * 128 + kt * 32 + q * 8);
#pragma unroll
        for (int ct = 0; ct < 8; ct++)
            acc[ct] = __builtin_amdgcn_mfma_f32_16x16x32_bf16(af, bfrag[ct][kt], acc[ct], 0, 0, 0);
    }
#pragma unroll
    for (int r = 0; r < 4; r++) {
        short8 ov;
#pragma unroll
        for (int ct = 0; ct < 8; ct++)
            ov[ct] = f2bfs(fmaxf(acc[ct][r] + bvv[ct], 0.f));
        *(short8*)&T[w * 16 + q * 4 + r][lid * 8] = ov;
    }
    __syncthreads();

    // ---- stage B: wave w = col chunk w; weights once, 4 rowtiles ----
#pragma unroll
    for (int ct = 0; ct < 8; ct++) {
        int pos = w * 128 + lid * 8 + ct;
        bvv[ct] = bsum[pos];
#pragma unroll
        for (int kt = 0; kt < 4; kt++)
            bfrag[ct][kt] = *(const short8*)(Wihp + (size_t)pos * 128 + kt * 32 + q * 8);
    }
#pragma unroll 1
    for (int rt = 0; rt < 4; rt++) {
#pragma unroll
        for (int ct = 0; ct < 8; ct++) acc[ct] = (floatx4)(0.f);
#pragma unroll
        for (int kt = 0; kt < 4; kt++) {
            short8 af = *(const short8*)&T[rt * 16 + lid][kt * 32 + q * 8];
#pragma unroll
            for (int ct = 0; ct < 8; ct++)
                acc[ct] = __builtin_amdgcn_mfma_f32_16x16x32_bf16(af, bfrag[ct][kt], acc[ct], 0, 0, 0);
        }
#pragma unroll
        for (int r = 0; r < 4; r++) {
            int row = rowbase + rt * 16 + q * 4 + r;
            if (row < N) {
                short8 ov;
#pragma unroll
                for (int ct = 0; ct < 8; ct++)
                    ov[ct] = f2bfs(acc[ct][r] + bvv[ct]);
                *(short8*)(Yout + (size_t)row * 512 + w * 128 + lid * 8) = ov;
            }
        }
    }
}

// ---------------------------------------------------------------------------
// LSTM neighbor aggregation (r14/r17 plateau core).
// EPI=2 (layer 1): epilogue computes h1 = relu(h@Wl^T+bl+x@Wr^T) (8 waves,
//   col j=w*16+lid), xp2 = relu(h1@Wp2^T+bp2), Y2 = xp2@Wihp2^T+bsum2
//   (4 col-tiles/wave). X rows DMA'd (swizzled) into dead stage[0] at t=15.
// EPI=1 (layer 2): epilogue computes out = h@Wl2^T+bl2+h1@Wr2^T (waves 0-2).
// ---------------------------------------------------------------------------
template <int EPI>
__global__ __launch_bounds__(512, 4) void lstm_aggr(
    const bf16* __restrict__ Y,     // [N,512] PERMUTED, prescaled pre-activations
    const int* __restrict__ esrc,   // [N,16]
    const bf16* __restrict__ Whh,   // [512,128] prescaled by gate
    int N,
    // EPI==2:
    const bf16* __restrict__ X, const bf16* __restrict__ Wl, const bf16* __restrict__ bl,
    const bf16* __restrict__ Wr, const bf16* __restrict__ Wp2, const bf16* __restrict__ bp2,
    const bf16* __restrict__ Wihp2, const float* __restrict__ bsum2,
    bf16* __restrict__ h1out, bf16* __restrict__ Y2out,
    // EPI==1:
    const bf16* __restrict__ Wl2, const bf16* __restrict__ bl2,
    const bf16* __restrict__ Wr2, const bf16* __restrict__ h1in,
    void* __restrict__ outp, const int* __restrict__ oflag)
{
    __shared__ alignas(16) short stage[2][8][1024];  // [buf][wave][2KB slice]
    __shared__ alignas(16) bf16 hb[2][16][136];
    __shared__ int srcl[16][16];    // [t][node]

    const int tid = threadIdx.x;
    const int w = tid >> 6, l = tid & 63, q = l >> 4, lid = l & 15;
    const int nodebase = blockIdx.x * 16;   // N = 50000 = 3125*16, exact

    if (tid < 256) {
        int node = tid >> 4, t = tid & 15;
        srcl[t][node] = esrc[(size_t)(nodebase + node) * 16 + t];
    }

    // Whh A-fragments: wf[g][kt]; A-row = gatecol = g*128 + 16*w + lid
    short8 wf[4][4];
#pragma unroll
    for (int g = 0; g < 4; g++) {
        int gc = g * 128 + 16 * w + lid;
#pragma unroll
        for (int kt = 0; kt < 4; kt++)
            wf[g][kt] = *(const short8*)(Whh + (size_t)gc * 128 + kt * 32 + q * 8);
    }

    float c[4];
#pragma unroll
    for (int r = 0; r < 4; r++) c[r] = 0.f;

    const int laneoff = w * 64 + q * 8;

    __syncthreads();   // srcl visible before first DMA

    // prologue: pairs 0,1 -> bufs 0,1 (oldest-first)
    {
        int s0 = srcl[0][lid];
        dma2(Y + (size_t)s0 * 512 + laneoff, &stage[0][w][0], &stage[0][w][512]);
        int s1 = srcl[1][lid];
        dma2(Y + (size_t)s1 * 512 + laneoff, &stage[1][w][0], &stage[1][w][512]);
    }

#pragma unroll 2
    for (int t = 0; t < 16; t++) {
        const int cb = t & 1;

        if (t == 15) asm volatile("s_waitcnt vmcnt(0)" ::: "memory");
        else         asm volatile("s_waitcnt vmcnt(2)" ::: "memory");

        // stage[0] is dead at t=15 (pair-14 retired): DMA the epilogue's 16
        // row-vectors (X for EPI=2, h1 for EPI=1) with rule-21 pre-swizzle:
        // lane loads chunk lid^(row&7); LDS stays linear; reads XOR back.
        if (EPI && t == 15 && w < 4) {
            int row = w * 4 + q;
            const bf16* src = (EPI == 2) ? X : h1in;
            const bf16* gp = src + (size_t)(nodebase + row) * 128 + (lid ^ (row & 7)) * 8;
            dma1(gp, (char*)&stage[0][0][0] + w * 1024);
        }

        int snext = (t < 14) ? srcl[t + 2][lid] : 0;

        floatx4 acc[4];
        {
            const short* wbuf = &stage[cb][w][0];
            short8 y0 = *(const short8*)&wbuf[q * 256 + lid * 8];
            short8 y1 = *(const short8*)&wbuf[q * 256 + 128 + lid * 8];
#pragma unroll
            for (int g = 0; g < 2; g++)
#pragma unroll
                for (int r = 0; r < 4; r++) {
                    acc[g][r]     = bfs2f(y0[g * 4 + r]);
                    acc[2 + g][r] = bfs2f(y1[g * 4 + r]);
                }
        }

        if (t) {   // h0 = 0: skip recurrent MFMA at t=0
#pragma unroll
            for (int kt = 0; kt < 4; kt++) {
                short8 bh = *(const short8*)&hb[cb][lid][kt * 32 + q * 8];
#pragma unroll
                for (int g = 0; g < 4; g++)
                    acc[g] = __builtin_amdgcn_mfma_f32_16x16x32_bf16(wf[g][kt], bh, acc[g], 0, 0, 0);
            }
        }

        {
            short4v hv;
#pragma unroll
            for (int r = 0; r < 4; r++)
                hv[r] = f2bfs(cell(acc[0][r], acc[1][r], acc[2][r], acc[3][r], c[r]));
            if (t < 15) *(short4v*)&hb[cb ^ 1][lid][16 * w + 4 * q] = hv;
            else        *(short4v*)&hb[0][lid][16 * w + 4 * q] = hv;   // cb^1 at t=15
        }

        if (t < 15) {
            asm volatile("s_waitcnt lgkmcnt(0)" ::: "memory");
            if (t < 14)
                dma2(Y + (size_t)snext * 512 + laneoff, &stage[cb][w][0], &stage[cb][w][512]);
            __builtin_amdgcn_s_barrier();   // hb exchange only — no vmcnt drain
        }
    }

    const short* xs = &stage[0][0][0];   // epilogue 16x128 row store (swizzled)

    if constexpr (EPI == 1) {
        asm volatile("s_waitcnt vmcnt(0)" ::: "memory");   // h1 rows landed
        short8 blf[4], brf[4];
        int j = w * 16 + lid;
        int jc = j < 40 ? j : 39;
        if (w < 3) {
#pragma unroll
            for (int kt = 0; kt < 4; kt++) {
                blf[kt] = *(const short8*)(Wl2 + (size_t)jc * 128 + kt * 32 + q * 8);
                brf[kt] = *(const short8*)(Wr2 + (size_t)jc * 128 + kt * 32 + q * 8);
            }
        }
        asm volatile("s_waitcnt lgkmcnt(0)" ::: "memory");
        __builtin_amdgcn_s_barrier();      // hb[0] complete
        if (w < 3) {                       // 3 col-tiles cover C=40
            floatx4 o = (floatx4)(0.f);
#pragma unroll
            for (int kt = 0; kt < 4; kt++) {
                short8 ah = *(const short8*)&hb[0][lid][kt * 32 + q * 8];
                o = __builtin_amdgcn_mfma_f32_16x16x32_bf16(ah, blf[kt], o, 0, 0, 0);
            }
#pragma unroll
            for (int kt = 0; kt < 4; kt++) {
                short8 a1 = *(const short8*)&xs[lid * 128 + (((kt * 4 + q) ^ (lid & 7)) << 3)];
                o = __builtin_amdgcn_mfma_f32_16x16x32_bf16(a1, brf[kt], o, 0, 0, 0);
            }
            float bv = bf2f(bl2[jc]);
            bool of32 = (*oflag != 0);
            if (j < 40) {
#pragma unroll
                for (int r = 0; r < 4; r++) {
                    int node = nodebase + q * 4 + r;
                    float v = o[r] + bv;
                    size_t idx = (size_t)node * 40 + j;
                    if (of32) ((float*)outp)[idx] = v;
                    else      ((bf16*)outp)[idx]  = f2bf(v);
                }
            }
        }
    }

    if constexpr (EPI == 2) {
        const int j = w * 16 + lid;        // 0..127
        short8 wlf[4], wrf[4];
#pragma unroll
        for (int kt = 0; kt < 4; kt++) {
            wlf[kt] = *(const short8*)(Wl + (size_t)j * 128 + kt * 32 + q * 8);
            wrf[kt] = *(const short8*)(Wr + (size_t)j * 128 + kt * 32 + q * 8);
        }
        float blv = bf2f(bl[j]);
        asm volatile("s_waitcnt vmcnt(0)" ::: "memory");   // X rows + weights
        asm volatile("s_waitcnt lgkmcnt(0)" ::: "memory");
        __builtin_amdgcn_s_barrier();      // hb[0] (h) complete

        // ---- h1 = relu(h@Wl^T + bl + x@Wr^T), col j ----
        floatx4 o = (floatx4)(0.f);
#pragma unroll
        for (int kt = 0; kt < 4; kt++) {
            short8 ah = *(const short8*)&hb[0][lid][kt * 32 + q * 8];
            o = __builtin_amdgcn_mfma_f32_16x16x32_bf16(ah, wlf[kt], o, 0, 0, 0);
        }
#pragma unroll
        for (int kt = 0; kt < 4; kt++) {
            short8 ax = *(const short8*)&xs[lid * 128 + (((kt * 4 + q) ^ (lid & 7)) << 3)];
            o = __builtin_amdgcn_mfma_f32_16x16x32_bf16(ax, wrf[kt], o, 0, 0, 0);
        }
        short8 wpf[4];
#pragma unroll
        for (int kt = 0; kt < 4; kt++)
            wpf[kt] = *(const short8*)(Wp2 + (size_t)j * 128 + kt * 32 + q * 8);
        float bpv = bf2f(bp2[j]);
#pragma unroll
        for (int r = 0; r < 4; r++) {
            short v = f2bfs(fmaxf(o[r] + blv, 0.f));
            hb[1][q * 4 + r][j] = *(bf16*)&v;
            h1out[(size_t)(nodebase + q * 4 + r) * 128 + j] = *(bf16*)&v;
        }
        asm volatile("s_waitcnt lgkmcnt(0)" ::: "memory");
        __builtin_amdgcn_s_barrier();      // hb[1] = h1 complete

        // ---- xp2 = relu(h1@Wp2^T + bp2), col j ----
        floatx4 o2 = (floatx4)(0.f);
#pragma unroll
        for (int kt = 0; kt < 4; kt++) {
            short8 a1 = *(const short8*)&hb[1][lid][kt * 32 + q * 8];
            o2 = __builtin_amdgcn_mfma_f32_16x16x32_bf16(a1, wpf[kt], o2, 0, 0, 0);
        }
#pragma unroll
        for (int r = 0; r < 4; r++) {
            short v = f2bfs(fmaxf(o2[r] + bpv, 0.f));
            hb[0][q * 4 + r][j] = *(bf16*)&v;
        }
        asm volatile("s_waitcnt lgkmcnt(0)" ::: "memory");
        __builtin_amdgcn_s_barrier();      // hb[0] = xp2 complete

        // ---- Y2 = xp2@Wihp2^T + bsum2; wave w covers cols [w*64, w*64+64) ----
        short8 axf[4];
#pragma unroll
        for (int kt = 0; kt < 4; kt++)
            axf[kt] = *(const short8*)&hb[0][lid][kt * 32 + q * 8];
#pragma unroll 1
        for (int tt = 0; tt < 4; tt++) {
            int pos = w * 64 + tt * 16 + lid;
            short8 wf2[4];
#pragma unroll
            for (int kt = 0; kt < 4; kt++)
                wf2[kt] = *(const short8*)(Wihp2 + (size_t)pos * 128 + kt * 32 + q * 8);
            float bs = bsum2[pos];
            floatx4 o3 = (floatx4)(0.f);
#pragma unroll
            for (int kt = 0; kt < 4; kt++)
                o3 = __builtin_amdgcn_mfma_f32_16x16x32_bf16(axf[kt], wf2[kt], o3, 0, 0, 0);
#pragma unroll
            for (int r = 0; r < 4; r++)
                Y2out[(size_t)(nodebase + q * 4 + r) * 512 + pos] = f2bf(o3[r] + bs);
        }
    }
}

extern "C" void kernel_launch(void* const* d_in, const int* in_sizes, int n_in,
                              void* d_out, int out_size, void* d_ws, size_t ws_size,
                              hipStream_t stream)
{
    const int N = 50000;
    const int* es = (const int*)d_in[1];
    char* ws = (char*)d_ws;

    struct Ent { int di; int di2; int mode; };
    Ent ents[17] = {
        {0,  -1, 0},
        {8,  -1, 0}, {9,  -1, 0},            // Wp1, bp1
        {10, -1, 2}, {11, -1, 1},            // Wihp1, Whh1
        {12, 13, 3},                         // bsum1 (f32)
        {14, -1, 0}, {15, -1, 0}, {16, -1, 0},  // Wl1, bl1, Wr1
        {17, -1, 0}, {18, -1, 0},            // Wp2, bp2
        {19, -1, 2}, {20, -1, 1},            // Wihp2, Whh2
        {21, 22, 3},                         // bsum2 (f32)
        {23, -1, 0}, {24, -1, 0}, {25, -1, 0},  // Wl2, bl2, Wr2
    };
    bf16* conv[17];
    size_t off = 0;
    CvtAll ca;
    for (int k = 0; k < 17; k++) {
        conv[k] = (bf16*)ws + off;
        int n = in_sizes[ents[k].di];
        ca.t[k].src  = d_in[ents[k].di];
        ca.t[k].src2 = ents[k].di2 >= 0 ? d_in[ents[k].di2] : nullptr;
        ca.t[k].dst  = conv[k];
        ca.t[k].n    = n;
        ca.t[k].mode = ents[k].mode;
        size_t elems = (ents[k].mode == 3) ? (size_t)n * 2 : (size_t)n;  // f32 dst
        off += (elems + 63) & ~(size_t)63;
    }
    // compact layout: conv @0 (~14MB), flag @14MB, Y1 @15MB (51.2MB),
    // h1 @67MB (12.8MB), Y2 @80MB (51.2MB) -> needs ~132MB workspace
    int* flag  = (int*)(ws + ((size_t)14 << 20));
    bf16* Y1   = (bf16*)(ws + ((size_t)15 << 20));
    bf16* h1   = (bf16*)(ws + ((size_t)67 << 20));
    bf16* Y2   = (bf16*)(ws + ((size_t)80 << 20));

    const bf16 *xc   = conv[0];
    const bf16 *Wp1  = conv[1],  *bp1 = conv[2];
    const bf16 *Wihp1 = conv[3], *Whh1 = conv[4];
    const float *bsum1 = (const float*)conv[5];
    const bf16 *Wl1 = conv[6], *bl1 = conv[7], *Wr1 = conv[8];
    const bf16 *Wp2 = conv[9], *bp2 = conv[10];
    const bf16 *Wihp2 = conv[11], *Whh2 = conv[12];
    const float *bsum2 = (const float*)conv[13];
    const bf16 *Wl2 = conv[14], *bl2 = conv[15], *Wr2 = conv[16];

    dim3 blk(256);
    const int gx = (N + 63) / 64;    // 782
    const int gl = N / 16;           // 3125 (exact)

    convert_inputs<<<dim3(1024), blk, 0, stream>>>(ca, flag);

    // ---- layer 1: xp1 -> Y1 ----
    fused_xp_y<<<dim3(gx), blk, 0, stream>>>(xc, Wp1, bp1, Wihp1, bsum1, Y1, N);

    // ---- lstm1 + fused {lin1, xp2, Y2} epilogue ----
    lstm_aggr<2><<<dim3(gl), dim3(512), 0, stream>>>(
        Y1, es, Whh1, N,
        xc, Wl1, bl1, Wr1, Wp2, bp2, Wihp2, bsum2, h1, Y2,
        nullptr, nullptr, nullptr, nullptr, nullptr, nullptr);

    // ---- lstm2 + fused final linear ----
    lstm_aggr<1><<<dim3(gl), dim3(512), 0, stream>>>(
        Y2, es, Whh2, N,
        nullptr, nullptr, nullptr, nullptr, nullptr, nullptr, nullptr, nullptr,
        nullptr, nullptr,
        Wl2, bl2, Wr2, h1, d_out, flag);
}